// Round 4
// baseline (809.470 us; speedup 1.0000x reference)
//
#include <hip/hip_runtime.h>
#include <hip/hip_bf16.h>
#include <math.h>

typedef unsigned short u16;
typedef __attribute__((ext_vector_type(8))) __bf16 bf16x8;
typedef __attribute__((ext_vector_type(4))) float f32x4;

__device__ __forceinline__ u16 f2b(float f) {
  unsigned u = __builtin_bit_cast(unsigned, f);
  u += 0x7fffu + ((u >> 16) & 1u);
  return (u16)(u >> 16);
}
__device__ __forceinline__ float b2f(u16 h) {
  unsigned u = ((unsigned)h) << 16;
  return __builtin_bit_cast(float, u);
}

__device__ __forceinline__ void gld_lds16(const u16* g, u16* l) {
  __builtin_amdgcn_global_load_lds(
      (const __attribute__((address_space(1))) unsigned int*)g,
      (__attribute__((address_space(3))) unsigned int*)l, 16, 0, 0);
}

#define MFMA16(a, b, c) \
  c = __builtin_amdgcn_mfma_f32_16x16x32_bf16(a, b, c, 0, 0, 0)

// ---------------- 128x128 BT-form GEMM tile body (m97 structure) -----------
// used by k_score and k_pv (load-balance via many blocks beats per-block eff.)
template <class FC>
__device__ __forceinline__ void gemm128_body(const u16* A, int lda,
                                             const u16* B, int ldb, FC fc,
                                             int m0, int n0, int K) {
  __shared__ __align__(16) u16 As[128 * 64];
  __shared__ __align__(16) u16 Bs[128 * 64];
  const int tid = threadIdx.x;
  const int wave = tid >> 6;
  const int lane = tid & 63;
  const int srow = lane >> 3;
  const int scol = ((lane & 7) ^ srow) * 8;
  const int wm = (wave & 1) * 64;
  const int wn = (wave >> 1) * 64;
  const int fm = lane & 15;
  const int fs = fm & 7;

  const u16* Abase = A + (size_t)m0 * lda;
  const u16* Bbase = B + (size_t)n0 * ldb;
  const size_t aLane = (size_t)(wave * 8 + srow) * lda + scol;
  const size_t bLane = (size_t)(wave * 8 + srow) * ldb + scol;

  f32x4 acc[4][4];
#pragma unroll
  for (int i = 0; i < 4; ++i)
#pragma unroll
    for (int j = 0; j < 4; ++j) acc[i][j] = (f32x4){0.f, 0.f, 0.f, 0.f};

  for (int k0 = 0; k0 < K; k0 += 64) {
#pragma unroll
    for (int c = 0; c < 4; ++c) {
      gld_lds16(Abase + (aLane + (size_t)(c * 32) * lda + k0),
                &As[(c * 4 + wave) * 512]);
      gld_lds16(Bbase + (bLane + (size_t)(c * 32) * ldb + k0),
                &Bs[(c * 4 + wave) * 512]);
    }
    __syncthreads();
#pragma unroll
    for (int kk = 0; kk < 2; ++kk) {
      const int cb = kk * 4 + (lane >> 4);
      const int p8 = (cb ^ fs) * 8;
      bf16x8 af[4], bfr[4];
#pragma unroll
      for (int i = 0; i < 4; ++i)
        af[i] = *(const bf16x8*)&As[(wm + i * 16 + fm) * 64 + p8];
#pragma unroll
      for (int j = 0; j < 4; ++j)
        bfr[j] = *(const bf16x8*)&Bs[(wn + j * 16 + fm) * 64 + p8];
#pragma unroll
      for (int i = 0; i < 4; ++i)
#pragma unroll
        for (int j = 0; j < 4; ++j) MFMA16(af[i], bfr[j], acc[i][j]);
    }
    __syncthreads();
  }
  const int er = lane >> 4;
#pragma unroll
  for (int i = 0; i < 4; ++i)
#pragma unroll
    for (int j = 0; j < 4; ++j)
#pragma unroll
      for (int r = 0; r < 4; ++r) {
        int m = m0 + wm + i * 16 + er * 4 + r;
        int n = n0 + wn + j * 16 + fm;
        fc(m, n, acc[i][j][r]);
      }
}

// ---------------- 256x256 8-phase BT-form GEMM body (faithful m201 port) ---
// 512 thr = 8 waves (2M x 4N), per-wave 128x64, BK=64, LDS 128KiB dbuf.
// 4 phases per K-tile T (buf=T&1), each = one C-quadrant x K=64 (16 MFMA):
//  ph1 (m0-3,n0-1): ds_read A-rows m0-3 @kk0,kk1 (8) + B n0-1 @kk0,kk1 (4)
//                   stage T+1.A.h1 -> As[buf^1]; lgkm(8); BAR; lgkm0; 16 MFMA; BAR
//  ph2 (m0-3,n2-3): ds_read B n2-3 (4); stage T+1.B.h1 -> Bs[buf^1]
//                   BAR; lgkm0; 16 MFMA; BAR
//  ph3 (m4-7,n0-1): ds_read A-rows m4-7 (8); stage T+2.B.h0 -> Bs[buf]
//                   BAR; lgkm0; 16 MFMA; BAR
//  ph4 (m4-7,n2-3): 0 ds_read; stage T+2.A.h0 -> As[buf]
//                   BAR; 16 MFMA; vmcnt(4); BAR
// Hazards: Bs[buf] fully read by ph2 (each wave reads only its own 64-col
// band, n0-3 across ph1/ph2) -> ph3 stage safe; As[buf] fully read by ph3
// (each wr-half reads its 128 rows across ph1/ph3) -> ph4 stage safe;
// buf^1 untouched by T's reads -> ph1/ph2 stages safe. vmcnt(4) at ph4
// retires exactly tile T+1's 4 half-tiles (outstanding = 6 half-tiles,
// leaves T+2's 2 in flight); trailing barrier publishes. lgkm0 always
// precedes the trailing barrier of its phase. Requires nkt >= 2.
// Per-acc accumulation order (kk0 then kk1, K-tiles ascending) identical
// to the 2-phase body -> bit-identical results.
template <class FC>
__device__ __forceinline__ void gemm256_body(const u16* A, int lda,
                                             const u16* B, int ldb, FC fc,
                                             int m0, int n0, int K) {
  __shared__ __align__(16) u16 As[2][16384];
  __shared__ __align__(16) u16 Bs[2][16384];
  const int tid = threadIdx.x;
  const int wave = tid >> 6;
  const int lane = tid & 63;
  const int wr = wave >> 2;  // 0..1 (M)
  const int wc = wave & 3;   // 0..3 (N)
  const int fm = lane & 15;
  const int cb4 = lane >> 4;  // 0..3
  const int fs = fm & 7;
  const int srow = lane >> 3;
  const int scol = ((lane & 7) ^ srow) * 8;  // inverse-swizzled global col

  const u16* Ab = A + (size_t)(m0 + srow) * lda + scol;
  const u16* Bb = B + (size_t)(n0 + srow) * ldb + scol;

  const int paRow = (wr * 128 + fm) * 64;
  const int pbRow = (wc * 64 + fm) * 64;
  const int q0 = (cb4 ^ fs) * 8;  // phys chunk offset, kk0
  const int q1 = q0 ^ 32;         // kk1

  f32x4 acc[8][4];
#pragma unroll
  for (int m = 0; m < 8; ++m)
#pragma unroll
    for (int n = 0; n < 4; ++n) acc[m][n] = (f32x4){0.f, 0.f, 0.f, 0.f};

  // stage one half-tile (h: 0 = rows 0..127, 1 = rows 128..255): 2 loads/thr
  auto stA = [&](int bi, int h, int kg) {
    const u16* g = Ab + (size_t)(h * 128 + wave * 8) * lda + kg;
    gld_lds16(g, &As[bi][h * 8192 + wave * 512]);
    gld_lds16(g + (size_t)64 * lda, &As[bi][h * 8192 + (wave + 8) * 512]);
  };
  auto stB = [&](int bi, int h, int kg) {
    const u16* g = Bb + (size_t)(h * 128 + wave * 8) * ldb + kg;
    gld_lds16(g, &Bs[bi][h * 8192 + wave * 512]);
    gld_lds16(g + (size_t)64 * ldb, &Bs[bi][h * 8192 + (wave + 8) * 512]);
  };

  const int nkt = K >> 6;  // call sites guarantee nkt >= 2

  // prologue: T0 all 4 half-tiles + T1.{B.h0, A.h0} (as if from T-1.ph3/4);
  // vmcnt(4) retires T0's 8 loads, leaves T1's 4 in flight.
  stB(0, 0, 0);
  stA(0, 0, 0);
  stA(0, 1, 0);
  stB(0, 1, 0);
  stB(1, 0, 64);
  stA(1, 0, 64);
  asm volatile("s_waitcnt vmcnt(4)" ::: "memory");
  __builtin_amdgcn_s_barrier();

  int buf = 0;
  for (int T = 0; T < nkt; ++T, buf ^= 1) {
    const int kc = T * 64;
    const bool sT1 = (T + 1) < nkt;
    const bool sT2 = (T + 2) < nkt;
    bf16x8 a0[4], a1[4], b0[4], b1[4];
    // ---- ph1 (m0-3, n0-1): 12 ds_read; stage T+1.A.h1
#pragma unroll
    for (int m = 0; m < 4; ++m) {
      a0[m] = *(const bf16x8*)&As[buf][paRow + m * 1024 + q0];
      a1[m] = *(const bf16x8*)&As[buf][paRow + m * 1024 + q1];
    }
#pragma unroll
    for (int n = 0; n < 2; ++n) {
      b0[n] = *(const bf16x8*)&Bs[buf][pbRow + n * 1024 + q0];
      b1[n] = *(const bf16x8*)&Bs[buf][pbRow + n * 1024 + q1];
    }
    if (sT1) stA(buf ^ 1, 1, kc + 64);
    asm volatile("s_waitcnt lgkmcnt(8)" ::: "memory");
    __builtin_amdgcn_s_barrier();
    asm volatile("s_waitcnt lgkmcnt(0)" ::: "memory");
    __builtin_amdgcn_sched_barrier(0);
    __builtin_amdgcn_s_setprio(1);
#pragma unroll
    for (int m = 0; m < 4; ++m) {
      MFMA16(a0[m], b0[0], acc[m][0]);
      MFMA16(a0[m], b0[1], acc[m][1]);
    }
#pragma unroll
    for (int m = 0; m < 4; ++m) {
      MFMA16(a1[m], b1[0], acc[m][0]);
      MFMA16(a1[m], b1[1], acc[m][1]);
    }
    __builtin_amdgcn_s_setprio(0);
    __builtin_amdgcn_s_barrier();
    // ---- ph2 (m0-3, n2-3): 4 ds_read; stage T+1.B.h1
#pragma unroll
    for (int n = 2; n < 4; ++n) {
      b0[n] = *(const bf16x8*)&Bs[buf][pbRow + n * 1024 + q0];
      b1[n] = *(const bf16x8*)&Bs[buf][pbRow + n * 1024 + q1];
    }
    if (sT1) stB(buf ^ 1, 1, kc + 64);
    __builtin_amdgcn_s_barrier();
    asm volatile("s_waitcnt lgkmcnt(0)" ::: "memory");
    __builtin_amdgcn_sched_barrier(0);
    __builtin_amdgcn_s_setprio(1);
#pragma unroll
    for (int m = 0; m < 4; ++m) {
      MFMA16(a0[m], b0[2], acc[m][2]);
      MFMA16(a0[m], b0[3], acc[m][3]);
    }
#pragma unroll
    for (int m = 0; m < 4; ++m) {
      MFMA16(a1[m], b1[2], acc[m][2]);
      MFMA16(a1[m], b1[3], acc[m][3]);
    }
    __builtin_amdgcn_s_setprio(0);
    __builtin_amdgcn_s_barrier();
    // ---- ph3 (m4-7, n0-1): 8 ds_read; stage T+2.B.h0
#pragma unroll
    for (int m = 0; m < 4; ++m) {
      a0[m] = *(const bf16x8*)&As[buf][paRow + (m + 4) * 1024 + q0];
      a1[m] = *(const bf16x8*)&As[buf][paRow + (m + 4) * 1024 + q1];
    }
    if (sT2) stB(buf, 0, kc + 128);
    __builtin_amdgcn_s_barrier();
    asm volatile("s_waitcnt lgkmcnt(0)" ::: "memory");
    __builtin_amdgcn_sched_barrier(0);
    __builtin_amdgcn_s_setprio(1);
#pragma unroll
    for (int m = 0; m < 4; ++m) {
      MFMA16(a0[m], b0[0], acc[m + 4][0]);
      MFMA16(a0[m], b0[1], acc[m + 4][1]);
    }
#pragma unroll
    for (int m = 0; m < 4; ++m) {
      MFMA16(a1[m], b1[0], acc[m + 4][0]);
      MFMA16(a1[m], b1[1], acc[m + 4][1]);
    }
    __builtin_amdgcn_s_setprio(0);
    __builtin_amdgcn_s_barrier();
    // ---- ph4 (m4-7, n2-3): 0 ds_read; stage T+2.A.h0; vmcnt once/K-tile
    if (sT2) stA(buf, 0, kc + 128);
    __builtin_amdgcn_s_barrier();
    __builtin_amdgcn_s_setprio(1);
#pragma unroll
    for (int m = 0; m < 4; ++m) {
      MFMA16(a0[m], b0[2], acc[m + 4][2]);
      MFMA16(a0[m], b0[3], acc[m + 4][3]);
    }
#pragma unroll
    for (int m = 0; m < 4; ++m) {
      MFMA16(a1[m], b1[2], acc[m + 4][2]);
      MFMA16(a1[m], b1[3], acc[m + 4][3]);
    }
    __builtin_amdgcn_s_setprio(0);
    if (sT2) {
      asm volatile("s_waitcnt vmcnt(4)" ::: "memory");
    } else if (sT1) {
      asm volatile("s_waitcnt vmcnt(0)" ::: "memory");
    }
    __builtin_amdgcn_s_barrier();
  }

  const int er = lane >> 4;
#pragma unroll
  for (int m = 0; m < 8; ++m)
#pragma unroll
    for (int n = 0; n < 4; ++n)
#pragma unroll
      for (int r = 0; r < 4; ++r)
        fc(m0 + wr * 128 + m * 16 + er * 4 + r, n0 + wc * 64 + n * 16 + fm,
           acc[m][n][r]);
}

// ---------------- epilogue functors ----------------
struct EQKV {
  u16* qb;
  u16* kb;
  float* vout;
  const float* bias;
  __device__ __forceinline__ void operator()(int m, int n, float v) const {
    v += bias[n];
    int b = m >> 11, l = m & 2047;
    int part = n >> 11, nn = n & 2047, h = nn >> 10, d = nn & 1023;
    size_t idx = ((size_t)((b << 1) + h) * 2048 + l) * 1024 + d;
    if (part == 0)
      qb[idx] = f2b(v);
    else if (part == 1)
      kb[idx] = f2b(v);
    else
      vout[idx] = v;
  }
};
struct EScoreB {
  u16* S;
  __device__ __forceinline__ void operator()(int m, int n, float v) const {
    S[((size_t)m << 11) + n] = f2b(v * 0.03125f + (n > m ? -1.0e9f : 0.0f));
  }
};
struct EBf16 {
  u16* o;
  int ld;
  __device__ __forceinline__ void operator()(int m, int n, float v) const {
    o[(size_t)m * ld + n] = f2b(v);
  }
};
struct EOut {
  float* o;
  const float* bias;
  __device__ __forceinline__ void operator()(int m, int n, float v) const {
    o[((size_t)m << 11) + n] = v + bias[n];
  }
};

__device__ __forceinline__ u16* spz(u16* sp0, u16* sp1, int z) {
  return (z < 4) ? sp0 + (size_t)z * 4194304 : sp1 + (size_t)(z - 4) * 4194304;
}

// ---------------- kernels ----------------
__global__ void __launch_bounds__(256) k_cast3(const float* x, const float* w1,
                                               const float* w2, u16* xb,
                                               u16* w1b, u16* w2b) {
  long i = (long)(blockIdx.x * 256 + threadIdx.x) * 4;
  const float* src;
  u16* dst;
  long off;
  if (i < 16777216L) {
    src = x; dst = xb; off = i;
  } else if (i < 16777216L + 12582912L) {
    src = w1; dst = w1b; off = i - 16777216L;
  } else {
    src = w2; dst = w2b; off = i - 16777216L - 12582912L;
  }
  float4 f = *(const float4*)(src + off);
  ushort4 o;
  o.x = f2b(f.x);
  o.y = f2b(f.y);
  o.z = f2b(f.z);
  o.w = f2b(f.w);
  *(ushort4*)(dst + off) = o;
}

__global__ void __launch_bounds__(512, 2) k_qkv(const u16* xb, const u16* wb,
                                                const float* bias, u16* qb,
                                                u16* kb, float* vout) {
  gemm256_body(xb, 2048, wb, 2048, EQKV{qb, kb, vout, bias}, blockIdx.y * 256,
               blockIdx.x * 256, 2048);
}

// vectorized: thread t handles d = 2t, 2t+1 (ushort2/float2 accesses);
// per-element math identical to the scalar version (same __expf/__sincosf).
__global__ void __launch_bounds__(256) k_rope(u16* qb, u16* kb, float* kout) {
  int l = blockIdx.x;
  int t = threadIdx.x;
  float lf = (float)l;
  const float c0 = (float)(-9.210340371976184 / 1024.0);  // -ln(1e4)/1024
  float sa, ca, sb, cb;
  {
    float inva = __expf((float)(4 * t) * c0);
    __sincosf(lf * inva, &sa, &ca);
    float invb = __expf((float)(4 * t + 2) * c0);
    __sincosf(lf * invb, &sb, &cb);
  }
  const int d = 2 * t;
#pragma unroll
  for (int bh = 0; bh < 8; ++bh) {
    size_t base = ((size_t)bh * 2048 + l) * 1024;
    ushort2 x1 = *(const ushort2*)&qb[base + d];
    ushort2 x2 = *(const ushort2*)&qb[base + 512 + d];
    float a1 = b2f(x1.x), a2 = b2f(x2.x);
    float b1 = b2f(x1.y), b2 = b2f(x2.y);
    ushort2 q1 = {f2b(a1 * ca - a2 * sa), f2b(b1 * cb - b2 * sb)};
    ushort2 q2 = {f2b(a1 * sa + a2 * ca), f2b(b1 * sb + b2 * cb)};
    *(ushort2*)&qb[base + d] = q1;
    *(ushort2*)&qb[base + 512 + d] = q2;
    ushort2 y1 = *(const ushort2*)&kb[base + d];
    ushort2 y2 = *(const ushort2*)&kb[base + 512 + d];
    float k1a = b2f(y1.x), k2a = b2f(y2.x);
    float k1b = b2f(y1.y), k2b = b2f(y2.y);
    float r1a = k1a * ca - k2a * sa, r2a = k1a * sa + k2a * ca;
    float r1b = k1b * cb - k2b * sb, r2b = k1b * sb + k2b * cb;
    ushort2 ka = {f2b(r1a), f2b(r1b)};
    ushort2 kc = {f2b(r2a), f2b(r2b)};
    *(ushort2*)&kb[base + d] = ka;
    *(ushort2*)&kb[base + 512 + d] = kc;
    *(float2*)&kout[base + d] = make_float2(r1a, r1b);
    *(float2*)&kout[base + 512 + d] = make_float2(r2a, r2b);
  }
}

__global__ void __launch_bounds__(256) k_transpose_v(const float* v, u16* vt) {
  __shared__ u16 tile[64][65];
  int bh = blockIdx.z;
  int d0 = blockIdx.x * 64, l0 = blockIdx.y * 64;
  const float* vb = v + (size_t)bh * 2048 * 1024;
  u16* vtb = vt + (size_t)bh * 1024 * 2048;
  int t = threadIdx.x;
  int c = t & 63, r4 = t >> 6;
#pragma unroll
  for (int r = 0; r < 16; ++r) {
    int row = r * 4 + r4;
    tile[row][c] = f2b(vb[(size_t)(l0 + row) * 1024 + d0 + c]);
  }
  __syncthreads();
#pragma unroll
  for (int r = 0; r < 16; ++r) {
    int drow = r * 4 + r4;
    vtb[(size_t)(d0 + drow) * 2048 + l0 + c] = tile[c][drow];
  }
}

__global__ void __launch_bounds__(256) k_score(const u16* qb, const u16* kb,
                                               u16* sp0, u16* sp1) {
  int m0 = blockIdx.y * 128, n0 = blockIdx.x * 128;
  if (n0 > m0) return;
  int z = blockIdx.z;
  const u16* q = qb + (size_t)z * 2048 * 1024;
  const u16* k = kb + (size_t)z * 2048 * 1024;
  gemm128_body(q, 1024, k, 1024, EScoreB{spz(sp0, sp1, z)}, m0, n0, 1024);
}

// in-place softmax; probs zero-padded out to a 256-col boundary (covers both
// the 128-tile k_pv Keff=m0+128 and any 256 tiling).
__global__ void __launch_bounds__(256) k_softmax(u16* sp0, u16* sp1) {
  int l = blockIdx.x, z = blockIdx.y;
  u16* row = spz(sp0, sp1, z) + ((size_t)l << 11);
  int t = threadIdx.x;
  int jend = ((l >> 8) + 1) << 8;
  __shared__ float red[4];
  float vals[8];
  float mx = -1e30f;
#pragma unroll
  for (int i = 0; i < 8; ++i) {
    int j = i * 256 + t;
    float v = (j <= l) ? b2f(row[j]) : -1e30f;
    vals[i] = v;
    mx = fmaxf(mx, v);
  }
#pragma unroll
  for (int off = 32; off; off >>= 1) mx = fmaxf(mx, __shfl_down(mx, off));
  if ((t & 63) == 0) red[t >> 6] = mx;
  __syncthreads();
  mx = fmaxf(fmaxf(red[0], red[1]), fmaxf(red[2], red[3]));
  __syncthreads();
  float sum = 0.f;
#pragma unroll
  for (int i = 0; i < 8; ++i) {
    int j = i * 256 + t;
    float e = (j <= l) ? __expf(vals[i] - mx) : 0.f;
    vals[i] = e;
    sum += e;
  }
#pragma unroll
  for (int off = 32; off; off >>= 1) sum += __shfl_down(sum, off);
  if ((t & 63) == 0) red[t >> 6] = sum;
  __syncthreads();
  sum = red[0] + red[1] + red[2] + red[3];
  float is = 1.0f / sum;
#pragma unroll
  for (int i = 0; i < 8; ++i) {
    int j = i * 256 + t;
    if (j < jend) row[j] = f2b(vals[i] * is);
  }
}

// 128-tile, 1024 blocks (4/CU): causal K-length imbalance averages out,
// unlike 256-tile (256 blocks = 1/CU, gated by the K=2048 straggler).
__global__ void __launch_bounds__(256) k_pv(u16* sp0, u16* sp1, const u16* vt,
                                            u16* vh) {
  int z = blockIdx.z;
  int b = z >> 1, h = z & 1;
  int m0 = blockIdx.y * 128, n0 = blockIdx.x * 128;
  const u16* Pz = spz(sp0, sp1, z);
  const u16* vtb = vt + (size_t)z * 1024 * 2048;
  u16* outb = vh + (size_t)b * 2048 * 2048 + (size_t)h * 1024;
  int Keff = m0 + 128;  // causal: P zero-padded past row end
  gemm128_body(Pz, 2048, vtb, 2048, EBf16{outb, 2048}, m0, n0, Keff);
}

__global__ void __launch_bounds__(512, 2) k_out(const u16* vh, const u16* w2,
                                                const float* bias, float* out) {
  gemm256_body(vh, 2048, w2, 2048, EOut{out, bias}, blockIdx.y * 256,
               blockIdx.x * 256, 2048);
}

// ---------------- launch ----------------
extern "C" void kernel_launch(void* const* d_in, const int* in_sizes, int n_in,
                              void* d_out, int out_size, void* d_ws,
                              size_t ws_size, hipStream_t stream) {
  const float* x = (const float*)d_in[0];
  const float* w1 = (const float*)d_in[2];
  const float* b1 = (const float*)d_in[3];
  const float* w2 = (const float*)d_in[4];
  const float* b2 = (const float*)d_in[5];
  float* out = (float*)d_out;
  float* kout = out + (size_t)16777216;
  float* vout = kout + (size_t)16777216;

  char* ws = (char*)d_ws;
  u16* xb = (u16*)ws;
  ws += (size_t)33554432;
  u16* w1b = (u16*)ws;
  ws += (size_t)25165824;
  u16* w2b = (u16*)ws;
  ws += (size_t)8388608;
  u16* qb = (u16*)ws;
  ws += (size_t)33554432;
  u16* kb = (u16*)ws;
  ws += (size_t)33554432;
  u16* vtb = (u16*)ws;
  ws += (size_t)33554432;
  u16* sp1 = (u16*)ws;
  u16* sp0 = xb;
  u16* vh = qb;

  k_cast3<<<32768, 256, 0, stream>>>(x, w1, w2, xb, w1b, w2b);
  k_qkv<<<dim3(24, 32), 512, 0, stream>>>(xb, w1b, b1, qb, kb, vout);
  k_rope<<<2048, 256, 0, stream>>>(qb, kb, kout);
  k_transpose_v<<<dim3(16, 32, 8), 256, 0, stream>>>(vout, vtb);
  k_score<<<dim3(16, 16, 8), 256, 0, stream>>>(qb, kb, sp0, sp1);
  k_softmax<<<dim3(2048, 8), 256, 0, stream>>>(sp0, sp1);
  k_pv<<<dim3(8, 16, 8), 256, 0, stream>>>(sp0, sp1, vtb, vh);
  k_out<<<dim3(8, 32), 512, 0, stream>>>(vh, w2b, b2, out);
}